// Round 7
// baseline (259.621 us; speedup 1.0000x reference)
//
#include <hip/hip_runtime.h>

// GRU: B=8192 chains, T=512 steps, IN=5, H=7, fused heads.
// R7 (from R6 @129us, VALUBusy 71.5%): CHAIN-BOUND hypothesis (R6 evidence:
// chain cuts pay ~1:1, issue cuts pay 0). Replace exp2+rcp sigmoid/tanh
// (2 serial trans ops per block, 2 blocks serial per step) with the
// Eigen/XNNPACK rational tanh x*P(x^2)/Q(x^2) (deg 13/6, clamp +-7.905):
// chain/block ~45 cyc (one rcp, parallel to P-Horner) vs ~8+2*L_trans.
// Issue rises ~+40 cyc/step/wave -- intentional trade; discriminates
// chain-bound vs issue-bound.
// Layout (R4-R6, verified): 16 lanes/batch, lane l: slot0 = r row (l<8) /
// z row (l>=8), slot1 = n row (both halves); one sigmoid/lane + ror:8 swap;
// heads deferred 1 step, riding the systolic row_ror rotation. 2 waves/SIMD.

namespace {
constexpr int Bn = 8192;
constexpr int Tn = 512;
constexpr int INn = 5;
constexpr int Hn = 7;
constexpr int TILE = 32;
constexpr int NTILE = Tn / TILE;         // 16
constexpr int BPB = 16;                  // batches per block (256 thr / 16)
constexpr int XSTR = 164;                // padded floats/batch in LDS
constexpr long long OFF_OR = (long long)Bn * Tn * 3;
constexpr long long OFF_HL = OFF_OR + (long long)Bn * Tn;
}

typedef float v2f __attribute__((ext_vector_type(2)));

__device__ __forceinline__ v2f pk_fma(v2f a, v2f b, v2f c) {
    return __builtin_elementwise_fma(a, b, c);
}
__device__ __forceinline__ v2f splat2(float x) { return (v2f){x, x}; }

// Rational tanh (Eigen/XNNPACK float coefficients): tanh(x) ~ x*P(x^2)/Q(x^2)
// on |x|<=7.905 (clamped; tanh saturates to 1 within float there).
// Chain: fmed3(4) + mul(4) + max(P: 6 fma deep, Q: 3 fma + rcp) + 2 mul.
// Sanity: P(1)/Q(1) = 0.761594 = tanh(1).
__device__ __forceinline__ float ptanh(float y) {
    float x = __builtin_amdgcn_fmed3f(y, -7.90531f, 7.90531f);
    float u = x * x;
    float q = fmaf(u, 1.19825839466702e-06f, 1.18534705686654e-04f);
    q = fmaf(u, q, 2.26843463243900e-03f);
    q = fmaf(u, q, 4.89352518554385e-03f);
    float rq = __builtin_amdgcn_rcpf(q);      // starts early, parallel to P
    float p = fmaf(u, -2.76076847742355e-16f, 2.00018790482477e-13f);
    p = fmaf(u, p, -8.60467152213735e-11f);
    p = fmaf(u, p, 5.12229709037114e-08f);
    p = fmaf(u, p, 1.48572235717979e-05f);
    p = fmaf(u, p, 6.37261928875436e-04f);
    p = fmaf(u, p, 4.89352455891786e-03f);
    p = p * x;
    return p * rq;
}
__device__ __forceinline__ float fast_sigmoid(float v) {
    return fmaf(0.5f, ptanh(0.5f * v), 0.5f);
}
__device__ __forceinline__ float fast_tanh(float x) { return ptanh(x); }

template<int CTRL>
__device__ __forceinline__ float dppf(float v) {
    int r = __builtin_amdgcn_update_dpp(0, __builtin_bit_cast(int, v),
                                        CTRL, 0xF, 0xF, true);
    return __builtin_bit_cast(float, r);
}

__global__ __launch_bounds__(256, 2) void gru_fused_kernel(
    const float* __restrict__ x,     // [B, T, IN]
    const float* __restrict__ W_ih,  // [21, 5]
    const float* __restrict__ W_hh,  // [21, 7]
    const float* __restrict__ b_ih,  // [21]
    const float* __restrict__ b_hh,  // [21]
    const float* __restrict__ W_h0,  // [7, 1]
    const float* __restrict__ W_m,   // [3, 7]
    const float* __restrict__ b_m,   // [3]
    const float* __restrict__ W_r,   // [1, 7]
    const float* __restrict__ b_r,   // [1]
    float* __restrict__ out)
{
    __shared__ float lds_x[2][BPB * XSTR];   // 2 x 10.25 KB

    const int tid  = threadIdx.x;
    const int l    = tid & 15;           // lane within 16-lane batch group
    const int j    = l & 7;              // hidden-unit slot (7 = pad, clones 6)
    const int g    = tid >> 4;           // batch slot in block
    const int b    = blockIdx.x * BPB + g;
    const int jj   = (j < 7) ? j : 6;
    const bool lo8 = ((l & 8) == 0);
    const bool l4  = (l < 4);

    // ---- rotated, packed weights ----
    const int row0 = lo8 ? jj : (Hn + jj);   // r row (lo) / z row (hi)
    const int row1 = 2 * Hn + jj;            // n row (both halves)

    v2f whh_rot[8];
    float whd_rot[8];
    #pragma unroll
    for (int i = 0; i < 8; ++i) {
        const int k = (j - i) & 7;
        if (k < 7) {
            whh_rot[i] = (v2f){W_hh[row0 * Hn + k], W_hh[row1 * Hn + k]};
            whd_rot[i] = (l < 3) ? W_m[l * Hn + k]
                       : (l == 3) ? W_r[k] : 0.0f;
        } else {
            whh_rot[i] = (v2f){0.0f, 0.0f};
            whd_rot[i] = 0.0f;
        }
    }
    v2f wih01[INn];
    #pragma unroll
    for (int i = 0; i < INn; ++i)
        wih01[i] = (v2f){W_ih[row0 * INn + i], W_ih[row1 * INn + i]};
    const v2f biasH = (v2f){b_hh[row0], b_hh[row1]};
    const v2f biasP = (v2f){b_ih[row0], b_ih[row1]};
    const float bhead = (l < 3) ? b_m[l] : (l == 3) ? b_r[0] : 0.0f;

    float hj = W_h0[jj];

    const float* xb = x + (long long)b * (Tn * INn);
    float* om  = out + (long long)b * (Tn * 3);
    float* orr = out + OFF_OR + (long long)b * Tn;

    // deferred-head store pointer: at step s store head(h_s) to index s-1
    float* hp = (l < 3) ? (om + l - 3) : (orr - 1);
    const int hstride = (l < 3) ? 3 : 1;

    // ---- prologue: stage tile 0 (160 floats = 80 float2 per batch) ----
    float2 stage[5];
    #pragma unroll
    for (int i = 0; i < 5; ++i)
        stage[i] = *(const float2*)(xb + 2 * (l + 16 * i));

    int cur = 0;
    for (int tl = 0; tl < NTILE; ++tl) {
        #pragma unroll
        for (int i = 0; i < 5; ++i)
            *(float2*)&lds_x[cur][g * XSTR + 2 * (l + 16 * i)] = stage[i];
        __syncthreads();

        if (tl + 1 < NTILE) {
            const float* src = xb + (tl + 1) * (TILE * INn);
            #pragma unroll
            for (int i = 0; i < 5; ++i)
                stage[i] = *(const float2*)(src + 2 * (l + 16 * i));
        }

        // x for this tile as 8 chunks of 4 steps (20 floats = 5 float4),
        // register double-buffered.
        const float4* xq = (const float4*)&lds_x[cur][g * XSTR];
        float4 xbuf[2][5];
        #pragma unroll
        for (int k = 0; k < 5; ++k) xbuf[0][k] = xq[k];

        #pragma unroll
        for (int c = 0; c < 8; ++c) {
            if (c < 7) {
                #pragma unroll
                for (int k = 0; k < 5; ++k)
                    xbuf[(c + 1) & 1][k] = xq[(c + 1) * 5 + k];
            }
            const float* xcf = (const float*)xbuf[c & 1];

            #pragma unroll
            for (int ss = 0; ss < 4; ++ss) {
                const int tt = c * 4 + ss;

                // systolic rotation, all rors independent off hj:
                // hidden matvec (packed r|z,n) + head dot share it
                v2f accA = biasH;
                v2f accB = (v2f){0.0f, 0.0f};
                float hd = bhead;
                accA = pk_fma(whh_rot[0], splat2(hj), accA);
                hd = fmaf(whd_rot[0], hj, hd);
                {
                    float h1 = dppf<0x121>(hj);
                    accB = pk_fma(whh_rot[1], splat2(h1), accB);
                    hd = fmaf(whd_rot[1], h1, hd);
                    float h2 = dppf<0x122>(hj);
                    accA = pk_fma(whh_rot[2], splat2(h2), accA);
                    hd = fmaf(whd_rot[2], h2, hd);
                    float h3 = dppf<0x123>(hj);
                    accB = pk_fma(whh_rot[3], splat2(h3), accB);
                    hd = fmaf(whd_rot[3], h3, hd);
                    float h4 = dppf<0x124>(hj);
                    accA = pk_fma(whh_rot[4], splat2(h4), accA);
                    hd = fmaf(whd_rot[4], h4, hd);
                    float h5 = dppf<0x125>(hj);
                    accB = pk_fma(whh_rot[5], splat2(h5), accB);
                    hd = fmaf(whd_rot[5], h5, hd);
                    float h6 = dppf<0x126>(hj);
                    accA = pk_fma(whh_rot[6], splat2(h6), accA);
                    hd = fmaf(whd_rot[6], h6, hd);
                    float h7 = dppf<0x127>(hj);
                    accB = pk_fma(whh_rot[7], splat2(h7), accB);
                    hd = fmaf(whd_rot[7], h7, hd);
                }
                v2f accH = accA + accB;          // (g0, g1) hidden-only

                // input projection (r multiplies hidden part only)
                v2f accP = biasP;
                #pragma unroll
                for (int i = 0; i < INn; ++i)
                    accP = pk_fma(wih01[i], splat2(xcf[5 * ss + i]), accP);

                // deferred head(h_t) -> index t-1 (guard folds away for tt>0)
                if ((tl > 0 || tt > 0) && l4) *hp = hd;
                hp += hstride;

                // gates (rational tanh/sigmoid: short chain, one rcp each)
                float s  = fast_sigmoid(accH[0] + accP[0]);
                float sv = dppf<0x128>(s);       // row_ror:8 half-swap
                float r_val = lo8 ? s : sv;
                float z_val = lo8 ? sv : s;
                float n = fast_tanh(fmaf(r_val, accH[1], accP[1]));
                hj = n + z_val * (hj - n);       // (1-z)*n + z*h
            }
        }
        cur ^= 1;
    }

    // epilogue: head of final h (one more rotation), stored at index T-1
    {
        float hd = bhead;
        hd = fmaf(whd_rot[0], hj, hd);
        hd = fmaf(whd_rot[1], dppf<0x121>(hj), hd);
        hd = fmaf(whd_rot[2], dppf<0x122>(hj), hd);
        hd = fmaf(whd_rot[3], dppf<0x123>(hj), hd);
        hd = fmaf(whd_rot[4], dppf<0x124>(hj), hd);
        hd = fmaf(whd_rot[5], dppf<0x125>(hj), hd);
        hd = fmaf(whd_rot[6], dppf<0x126>(hj), hd);
        hd = fmaf(whd_rot[7], dppf<0x127>(hj), hd);
        if (l4) *hp = hd;
    }

    // h_last: [1, B, H]
    if (l < Hn) out[OFF_HL + (long long)b * Hn + l] = hj;
}

extern "C" void kernel_launch(void* const* d_in, const int* in_sizes, int n_in,
                              void* d_out, int out_size, void* d_ws, size_t ws_size,
                              hipStream_t stream) {
    const float* x    = (const float*)d_in[0];
    // d_in[1] = batch_size (scalar), unused — B compiled in
    const float* W_ih = (const float*)d_in[2];
    const float* W_hh = (const float*)d_in[3];
    const float* b_ih = (const float*)d_in[4];
    const float* b_hh = (const float*)d_in[5];
    const float* W_h0 = (const float*)d_in[6];
    const float* W_m  = (const float*)d_in[7];
    const float* b_m  = (const float*)d_in[8];
    const float* W_r  = (const float*)d_in[9];
    const float* b_r  = (const float*)d_in[10];
    float* out = (float*)d_out;

    dim3 grid(Bn / BPB);  // 512 blocks
    dim3 block(256);      // 16 batch elements x 16 lanes
    gru_fused_kernel<<<grid, block, 0, stream>>>(x, W_ih, W_hh, b_ih, b_hh,
                                                 W_h0, W_m, b_m, W_r, b_r, out);
}